// Round 1
// baseline (4166.729 us; speedup 1.0000x reference)
//
#include <hip/hip_runtime.h>

// DiffusionConvolution: out[b,n,o] = bias[o] + sum_{s,k,d} (A_s^k x0)[n,(d,b)] * W[(3s+k)*64+d, o]
// B=32, N=20000, D=OUT=64, K=2, E=640000 per support.
// Internal node-feature layout: x[n][b*64+d] (164 MB per buffer).
// Structure: per support, build CSR on-device, then
//   S1: X1 = A * x0 (gather from inputs layout) + fused projection with W_{s,1} into out
//   S2:      A * X1 (gather from X layout)      + fused projection with W_{s,2} into out
// k=0 term + bias handled by k0_gemm (initializes out; harness poisons d_out each call).
// Workspace: X1 (163.84 MB) + CSR arrays (~10.3 MB) ≈ 175 MB.

constexpr int B = 32;
constexpr int D = 64;
constexpr int C = B * D;   // 2048 features per node

__device__ __forceinline__ void fma4(float4& a, float s, const float4 b) {
  a.x = fmaf(s, b.x, a.x);
  a.y = fmaf(s, b.y, a.y);
  a.z = fmaf(s, b.z, a.z);
  a.w = fmaf(s, b.w, a.w);
}

// ---------------- CSR build ----------------

__global__ __launch_bounds__(256) void hist_k(const int* __restrict__ rows,
                                              int* __restrict__ counts, int E) {
  int e = blockIdx.x * 256 + threadIdx.x;
  if (e < E) atomicAdd(&counts[rows[e]], 1);
}

// single-block exclusive scan: counts[0..N) -> row_ptr[0..N]
__global__ __launch_bounds__(256) void scan_k(const int* __restrict__ counts,
                                              int* __restrict__ row_ptr, int N) {
  __shared__ int part[256];
  int t = threadIdx.x;
  int chunk = (N + 255) >> 8;
  int lo = t * chunk; if (lo > N) lo = N;
  int hi = lo + chunk; if (hi > N) hi = N;
  int s = 0;
  for (int i = lo; i < hi; ++i) s += counts[i];
  part[t] = s;
  __syncthreads();
  for (int off = 1; off < 256; off <<= 1) {
    int x = (t >= off) ? part[t - off] : 0;
    __syncthreads();
    part[t] += x;
    __syncthreads();
  }
  int run = part[t] - s;  // exclusive prefix of this thread's chunk
  for (int i = lo; i < hi; ++i) { row_ptr[i] = run; run += counts[i]; }
  if (t == 255) row_ptr[N] = part[255];  // total = E
}

__global__ __launch_bounds__(256) void fill_k(const int* __restrict__ rows,
                                              const int* __restrict__ cols,
                                              const float* __restrict__ vals,
                                              const int* __restrict__ row_ptr,
                                              int* __restrict__ cursor,
                                              int* __restrict__ ecol,
                                              float* __restrict__ eval, int E) {
  int e = blockIdx.x * 256 + threadIdx.x;
  if (e < E) {
    int r = rows[e];
    int pos = row_ptr[r] + atomicAdd(&cursor[r], 1);
    ecol[pos] = cols[e];
    eval[pos] = vals[e];
  }
}

// ---------------- k=0 GEMM: out = bias + x0 * (W rows 0..63 + rows 192..255) ----------------
// grid: (ceil(N/64), B); block 256. Tile: 64 n-rows x 64 outs, thread tile 2n x 8o.

__global__ __launch_bounds__(256) void k0_gemm(const float4* __restrict__ inp4,
                                               const float4* __restrict__ W4,
                                               const float4* __restrict__ bias4,
                                               float4* __restrict__ out4, int N) {
  __shared__ float sA[64 * 65];     // padded (+1 per row) to break bank conflicts
  __shared__ float4 sW[64 * 16];    // Wc = W[0:64] + W[192:256], [d][o]
  int t = threadIdx.x;
  int b = blockIdx.y;
  int n0 = blockIdx.x * 64;

#pragma unroll
  for (int k = 0; k < 4; ++k) {
    int l = t + 256 * k;            // l in [0,1024): d = l>>4, o4 = l&15
    float4 w0 = W4[l];
    float4 w1 = W4[192 * 16 + l];
    w0.x += w1.x; w0.y += w1.y; w0.z += w1.z; w0.w += w1.w;
    sW[l] = w0;
  }
#pragma unroll
  for (int k = 0; k < 4; ++k) {
    int q = t + 256 * k;            // 64 rows x 16 float4
    int r = q >> 4, d4 = q & 15;
    int n = n0 + r;
    float4 v = {0.f, 0.f, 0.f, 0.f};
    if (n < N) v = inp4[(b * N + n) * 16 + d4];
    float* sp = &sA[r * 65 + d4 * 4];
    sp[0] = v.x; sp[1] = v.y; sp[2] = v.z; sp[3] = v.w;
  }
  __syncthreads();

  int np = t >> 3;                  // 0..31 -> rows np*2, np*2+1
  int og = t & 7;                   // outs og*8 .. og*8+7
  float4 bz0 = bias4[og * 2], bz1 = bias4[og * 2 + 1];
  float4 a00 = bz0, a01 = bz1, a10 = bz0, a11 = bz1;
  const float* ap0 = &sA[(np * 2) * 65];
  const float* ap1 = ap0 + 65;
#pragma unroll
  for (int d = 0; d < 64; ++d) {
    float x0 = ap0[d], x1 = ap1[d];
    float4 w0 = sW[d * 16 + og * 2];
    float4 w1 = sW[d * 16 + og * 2 + 1];
    fma4(a00, x0, w0); fma4(a01, x0, w1);
    fma4(a10, x1, w0); fma4(a11, x1, w1);
  }
  int n = n0 + np * 2;
  if (n < N) {
    out4[(b * N + n) * 16 + og * 2] = a00;
    out4[(b * N + n) * 16 + og * 2 + 1] = a01;
  }
  if (n + 1 < N) {
    out4[(b * N + n + 1) * 16 + og * 2] = a10;
    out4[(b * N + n + 1) * 16 + og * 2 + 1] = a11;
  }
}

// ---------------- SpMM + fused projection ----------------
// One block per output row n. Gathers E_row source rows (2048 floats each) into
// registers, optionally writes X, then projects acc (32b x 64d) through W slice
// (64d x 64o) and accumulates into out[b,n,o].

template <bool FROM_INPUTS, bool WRITE_X>
__global__ __launch_bounds__(256) void spmm_proj(const float4* __restrict__ src4,
                                                 const int* __restrict__ row_ptr,
                                                 const int* __restrict__ ecol,
                                                 const float* __restrict__ eval,
                                                 const float4* __restrict__ Wslice4,
                                                 float4* __restrict__ X4,
                                                 float4* __restrict__ out4, int N) {
  __shared__ float4 sW[64 * 16];   // 16 KB: [d][o4]
  __shared__ float sAcc[32 * 65];  // 8.32 KB padded: [b][d]
  int t = threadIdx.x;
  int n = blockIdx.x;

#pragma unroll
  for (int k = 0; k < 4; ++k) sW[t + 256 * k] = Wslice4[t + 256 * k];

  float4 acc0 = {0.f, 0.f, 0.f, 0.f};
  float4 acc1 = {0.f, 0.f, 0.f, 0.f};
  int start = row_ptr[n], end = row_ptr[n + 1];

  if (FROM_INPUTS) {
    // thread t covers features f=4t..4t+3 (b=t>>4) and f=1024+4t.. (b=16+(t>>4))
    const float4* p0 = src4 + (t >> 4) * (N * 16) + (t & 15);
    const float4* p1 = src4 + ((t >> 4) + 16) * (N * 16) + (t & 15);
    for (int e = start; e < end; ++e) {
      int col = ecol[e];
      float v = eval[e];
      fma4(acc0, v, p0[col * 16]);
      fma4(acc1, v, p1[col * 16]);
    }
  } else {
    for (int e = start; e < end; ++e) {
      int col = ecol[e];
      float v = eval[e];
      fma4(acc0, v, src4[col * 512 + t]);
      fma4(acc1, v, src4[col * 512 + 256 + t]);
    }
  }

  if (WRITE_X) {
    X4[n * 512 + t] = acc0;
    X4[n * 512 + 256 + t] = acc1;
  }

  {  // stash acc into padded (b,d) LDS layout
    int b = t >> 4;
    int d = (t & 15) * 4;
    float* s0 = &sAcc[b * 65 + d];
    s0[0] = acc0.x; s0[1] = acc0.y; s0[2] = acc0.z; s0[3] = acc0.w;
    float* s1 = &sAcc[(b + 16) * 65 + d];
    s1[0] = acc1.x; s1[1] = acc1.y; s1[2] = acc1.z; s1[3] = acc1.w;
  }
  __syncthreads();

  // mini-GEMM: thread -> (b = t>>3, outs og*8..og*8+7)
  int bb = t >> 3;
  int og = t & 7;
  float4 o0 = {0.f, 0.f, 0.f, 0.f};
  float4 o1 = {0.f, 0.f, 0.f, 0.f};
  const float* ap = &sAcc[bb * 65];
#pragma unroll
  for (int d = 0; d < 64; ++d) {
    float a = ap[d];
    fma4(o0, a, sW[d * 16 + og * 2]);
    fma4(o1, a, sW[d * 16 + og * 2 + 1]);
  }
  float4* op = out4 + (bb * N + n) * 16 + og * 2;
  float4 c0 = op[0], c1 = op[1];
  c0.x += o0.x; c0.y += o0.y; c0.z += o0.z; c0.w += o0.w;
  c1.x += o1.x; c1.y += o1.y; c1.z += o1.z; c1.w += o1.w;
  op[0] = c0;
  op[1] = c1;
}

// ---------------- launch ----------------

extern "C" void kernel_launch(void* const* d_in, const int* in_sizes, int n_in,
                              void* d_out, int out_size, void* d_ws, size_t ws_size,
                              hipStream_t stream) {
  const float* inp = (const float*)d_in[0];
  const int*   rws[2] = {(const int*)d_in[1], (const int*)d_in[4]};
  const int*   cls[2] = {(const int*)d_in[2], (const int*)d_in[5]};
  const float* vls[2] = {(const float*)d_in[3], (const float*)d_in[6]};
  const float* W    = (const float*)d_in[7];
  const float* bias = (const float*)d_in[8];
  float* out = (float*)d_out;

  const int N = in_sizes[0] / C;          // 20000
  const int Emax = (in_sizes[1] > in_sizes[4]) ? in_sizes[1] : in_sizes[4];

  // workspace layout
  char* ws = (char*)d_ws;
  float* X1 = (float*)ws;
  size_t off = (size_t)N * C * sizeof(float);            // 163.84 MB
  int*   ecol = (int*)(ws + off);   off += (size_t)Emax * 4;
  float* evalv = (float*)(ws + off); off += (size_t)Emax * 4;
  int*   row_ptr = (int*)(ws + off); off += (size_t)(N + 1) * 4;
  off = (off + 255) & ~(size_t)255;
  int*   counts = (int*)(ws + off);  off += (size_t)N * 4;
  (void)ws_size; (void)n_in; (void)out_size;  // needs ~175 MB of ws

  // out = bias + x0 * Wc   (k=0 term for both supports)
  dim3 g0((N + 63) / 64, B);
  k0_gemm<<<g0, 256, 0, stream>>>((const float4*)inp, (const float4*)W,
                                  (const float4*)bias, (float4*)out, N);

  for (int s = 0; s < 2; ++s) {
    const int E = in_sizes[s == 0 ? 1 : 4];
    const int* rows = rws[s];
    const int* cols = cls[s];
    const float* vals = vls[s];

    hipMemsetAsync(counts, 0, (size_t)N * 4, stream);
    hist_k<<<(E + 255) / 256, 256, 0, stream>>>(rows, counts, E);
    scan_k<<<1, 256, 0, stream>>>(counts, row_ptr, N);
    hipMemsetAsync(counts, 0, (size_t)N * 4, stream);
    fill_k<<<(E + 255) / 256, 256, 0, stream>>>(rows, cols, vals, row_ptr, counts,
                                                ecol, evalv, E);

    const float4* W1 = (const float4*)(W + (size_t)(s * 3 + 1) * 64 * 64);
    const float4* W2 = (const float4*)(W + (size_t)(s * 3 + 2) * 64 * 64);

    // hop 1: X1 = A*x0 (gather from inputs layout), project with W1
    spmm_proj<true, true><<<N, 256, 0, stream>>>((const float4*)inp, row_ptr, ecol,
                                                 evalv, W1, (float4*)X1,
                                                 (float4*)out, N);
    // hop 2: A*X1, project with W2 (X2 never materialized)
    spmm_proj<false, false><<<N, 256, 0, stream>>>((const float4*)X1, row_ptr, ecol,
                                                   evalv, W2, nullptr,
                                                   (float4*)out, N);
  }
}